// Round 13
// baseline (150.168 us; speedup 1.0000x reference)
//
#include <hip/hip_runtime.h>
#include <hip/hip_bf16.h>
#include <stdint.h>

// C = (B,16,16): diag (k,k)=sigmoid(x·Wd[k]+bd[k]); off (i,j)=-softplus(x·Wo[r]+bo[r])
// Permuted GEMM out[b][c], c=i*16+j. M=65536 N=256 K=1024, bf16 MFMA 16x16x32.
// R13: phase-decoupled. Block = 64 rows x 256 cols, 512 thr (8 waves, 4Mx2N),
// LDS = one 64x512-bf16 A half-panel (64 KB) -> 2 blocks/CU. Per K-half:
//   Phase 1 (pure stream, NO barriers inside): float4-load 128 KB of x,
//     pack fp32->bf16, XOR-swizzled ds_write.    [fillBuffer-like pattern]
//   Phase 2 (NO barriers, NO HBM): 16 chunks x {8 B-frags direct from
//     fragment-ordered L2 image -> regs, 1 A ds_read, 8 MFMA}.
// 4 barriers total. Cross-block overlap (2 blocks/CU) pipelines the phases.

typedef __bf16 bf16x8 __attribute__((ext_vector_type(8)));
typedef float f32x4 __attribute__((ext_vector_type(4)));

#define THREADS 512
#define BM 64
#define WBYTES 524288              // 32 chunk-images x 16 KB

__device__ __forceinline__ unsigned bf_rtne(unsigned u) {
  return (u + 0x7fffu + ((u >> 16) & 1u)) >> 16;
}
__device__ __forceinline__ unsigned pack2(float lo, float hi) {
  return bf_rtne(__float_as_uint(lo)) | (bf_rtne(__float_as_uint(hi)) << 16);
}

// W image, fragment order (R2/R8-verified mapping, 32-k chunks):
// (c,k): ch=k>>5, q=(k>>3)&3, e=k&7 -> byte = ch*16384 + q*4096 + c*16 + e*2
// Wave B-frag load = 4 contiguous 256B segments per instruction; L2-resident.
__global__ void prep_kernel(const float* __restrict__ Wd, const float* __restrict__ bd,
                            const float* __restrict__ Wo, const float* __restrict__ bo,
                            char* __restrict__ wbuf, float* __restrict__ bias) {
  const int c = blockIdx.x;    // 0..255 output col
  const int t = threadIdx.x;   // 0..255, 4 consecutive k each
  const int i = c >> 4, j = c & 15;
  const float* src;
  float b;
  if (i == j) { src = Wd + i * 1024; b = bd[i]; }
  else { int r = i * 15 + (j < i ? j : j - 1); src = Wo + r * 1024; b = bo[r]; }
  if (t == 0) bias[c] = b;
  const int kk = t * 4;
  const int ch = kk >> 5, q = (kk >> 3) & 3, e = kk & 7;
  float4 v = *reinterpret_cast<const float4*>(src + kk);
  uint2 h;
  h.x = pack2(v.x, v.y);
  h.y = pack2(v.z, v.w);
  *reinterpret_cast<uint2*>(wbuf + ch * 16384 + q * 4096 + c * 16 + e * 2) = h;
}

__global__ __launch_bounds__(THREADS, 4) void cap_main(
    const float* __restrict__ x, const char* __restrict__ wbuf,
    const float* __restrict__ bias, float* __restrict__ out) {
  __shared__ char smem[65536];   // A half-panel [64 rows][512 k] bf16, swizzled

  const int tid = threadIdx.x;
  const int wid = tid >> 6;
  const int lane = tid & 63;
  const int l15 = lane & 15;
  const int l4 = lane >> 4;
  const int wm = wid >> 1;       // 0..3: rows wm*16..+15
  const int wn = wid & 1;        // 0..1: cols wn*128..+127

  const size_t blkRow = (size_t)blockIdx.x * BM;

  // B-frag global base (fragment-ordered image): + chG*16384 + n*256
  const char* wb = wbuf + l4 * 4096 + (wn * 128 + l15) * 16;

  // A-frag LDS base: row (wm*16+l15), k-local bytes (c*64 + l4*16) ^ xor
  const unsigned abase = (unsigned)((wm * 16 + l15) * 1024);
  const unsigned axor = (unsigned)((l15 & 7) << 4);

  f32x4 acc[8];
#pragma unroll
  for (int n = 0; n < 8; ++n) acc[n] = (f32x4){0.f, 0.f, 0.f, 0.f};

  for (int kh = 0; kh < 2; ++kh) {
    // ---- Phase 1: pure stream of the 64x512 half-panel (128 KB fp32) ----
    // id = it*8192 + tid*16 floats; row = id>>9, k = id&511 (2KB segs/row-half)
#pragma unroll
    for (int it = 0; it < 4; ++it) {
      const int id = it * 8192 + tid * 16;
      const int r = id >> 9;
      const int k = id & 511;
      const float* src = x + (blkRow + (size_t)r) * 1024 + kh * 512 + k;
      float4 v0 = *reinterpret_cast<const float4*>(src);
      float4 v1 = *reinterpret_cast<const float4*>(src + 4);
      float4 v2 = *reinterpret_cast<const float4*>(src + 8);
      float4 v3 = *reinterpret_cast<const float4*>(src + 12);
      uint4 h0, h1;
      h0.x = pack2(v0.x, v0.y); h0.y = pack2(v0.z, v0.w);
      h0.z = pack2(v1.x, v1.y); h0.w = pack2(v1.z, v1.w);
      h1.x = pack2(v2.x, v2.y); h1.y = pack2(v2.z, v2.w);
      h1.z = pack2(v3.x, v3.y); h1.w = pack2(v3.z, v3.w);
      const unsigned rx = (unsigned)((r & 7) << 4);
      *reinterpret_cast<uint4*>(smem + r * 1024 + ((2 * k) ^ rx)) = h0;
      *reinterpret_cast<uint4*>(smem + r * 1024 + ((2 * k + 16) ^ rx)) = h1;
    }
    __syncthreads();

    // ---- Phase 2: 16 chunks, barrier-free, B direct from L2 image ----
#pragma unroll 4
    for (int c = 0; c < 16; ++c) {
      const char* wc = wb + (kh * 16 + c) * 16384;
      uint4 bu0 = *reinterpret_cast<const uint4*>(wc);
      uint4 bu1 = *reinterpret_cast<const uint4*>(wc + 256);
      uint4 bu2 = *reinterpret_cast<const uint4*>(wc + 512);
      uint4 bu3 = *reinterpret_cast<const uint4*>(wc + 768);
      uint4 bu4 = *reinterpret_cast<const uint4*>(wc + 1024);
      uint4 bu5 = *reinterpret_cast<const uint4*>(wc + 1280);
      uint4 bu6 = *reinterpret_cast<const uint4*>(wc + 1536);
      uint4 bu7 = *reinterpret_cast<const uint4*>(wc + 1792);
      bf16x8 af = *reinterpret_cast<const bf16x8*>(
          smem + abase + ((c * 64 + l4 * 16) ^ axor));
      acc[0] = __builtin_amdgcn_mfma_f32_16x16x32_bf16(af, *reinterpret_cast<bf16x8*>(&bu0), acc[0], 0, 0, 0);
      acc[1] = __builtin_amdgcn_mfma_f32_16x16x32_bf16(af, *reinterpret_cast<bf16x8*>(&bu1), acc[1], 0, 0, 0);
      acc[2] = __builtin_amdgcn_mfma_f32_16x16x32_bf16(af, *reinterpret_cast<bf16x8*>(&bu2), acc[2], 0, 0, 0);
      acc[3] = __builtin_amdgcn_mfma_f32_16x16x32_bf16(af, *reinterpret_cast<bf16x8*>(&bu3), acc[3], 0, 0, 0);
      acc[4] = __builtin_amdgcn_mfma_f32_16x16x32_bf16(af, *reinterpret_cast<bf16x8*>(&bu4), acc[4], 0, 0, 0);
      acc[5] = __builtin_amdgcn_mfma_f32_16x16x32_bf16(af, *reinterpret_cast<bf16x8*>(&bu5), acc[5], 0, 0, 0);
      acc[6] = __builtin_amdgcn_mfma_f32_16x16x32_bf16(af, *reinterpret_cast<bf16x8*>(&bu6), acc[6], 0, 0, 0);
      acc[7] = __builtin_amdgcn_mfma_f32_16x16x32_bf16(af, *reinterpret_cast<bf16x8*>(&bu7), acc[7], 0, 0, 0);
    }
    __syncthreads();   // A half no longer needed; next half may overwrite
  }

  // ---- epilogue (R4-verified pattern): activation -> LDS transpose ----
  const int rr2 = tid >> 5;            // 0..15 read-back row in band
  const int co = (tid & 31) * 8;       // read-back col (floats)
  const char* rdp = smem + rr2 * 1040 + co * 4;

#pragma unroll
  for (int p = 0; p < 4; ++p) {        // band p = rows p*16..+15 (wave wm==p)
    if (wm == p) {
#pragma unroll
      for (int n = 0; n < 8; ++n) {
        const int col = wn * 128 + n * 16 + l15;
        const float bv = bias[col];
        const bool diag = (col % 17) == 0;
#pragma unroll
        for (int j2 = 0; j2 < 4; ++j2) {
          const int rr = l4 * 4 + j2;
          float v = acc[n][j2] + bv;
          float e = __expf(-fabsf(v));
          float sig = (v >= 0.f) ? 1.f / (1.f + e) : e / (1.f + e);
          float sp = fmaxf(v, 0.f) + __logf(1.f + e);
          *reinterpret_cast<float*>(smem + rr * 1040 + col * 4) = diag ? sig : -sp;
        }
      }
    }
    __syncthreads();
    float4 o0 = *reinterpret_cast<const float4*>(rdp);
    float4 o1 = *reinterpret_cast<const float4*>(rdp + 16);
    float* orow = out + (blkRow + (size_t)(p * 16 + rr2)) * 256 + co;
    *reinterpret_cast<float4*>(orow) = o0;
    *reinterpret_cast<float4*>(orow + 4) = o1;
    __syncthreads();
  }
}

extern "C" void kernel_launch(void* const* d_in, const int* in_sizes, int n_in,
                              void* d_out, int out_size, void* d_ws, size_t ws_size,
                              hipStream_t stream) {
  const float* x = (const float*)d_in[0];
  const float* Wd = (const float*)d_in[1];
  const float* bd = (const float*)d_in[2];
  const float* Wo = (const float*)d_in[3];
  const float* bo = (const float*)d_in[4];
  float* out = (float*)d_out;
  char* wbuf = (char*)d_ws;                  // 512 KiB weight image
  float* bias = (float*)(wbuf + WBYTES);     // 1 KiB bias

  prep_kernel<<<dim3(256), dim3(256), 0, stream>>>(Wd, bd, Wo, bo, wbuf, bias);
  cap_main<<<dim3(1024), dim3(THREADS), 0, stream>>>(x, wbuf, bias, out);
}

// Round 14
// 146.420 us; speedup vs baseline: 1.0256x; 1.0256x over previous
//
#include <hip/hip_runtime.h>
#include <hip/hip_bf16.h>
#include <stdint.h>

// C = (B,16,16): diag (k,k)=sigmoid(x·Wd[k]+bd[k]); off (i,j)=-softplus(x·Wo[r]+bo[r])
// Permuted GEMM out[b][c], c=i*16+j. M=65536 N=256 K=1024, bf16 MFMA 16x16x32.
// R14: all-gload_lds x streaming with phase overlap. 512 blocks x 512 thr
// (8 waves). Block = 128 rows (4 panels of 32) x 256 cols. Per half-K of a
// panel: 64 KB fp32 staged via 64 global_load_lds (pre-swizzled source, linear
// dest); stage(h+1) issued BEFORE compute(h) so it flies under the MFMA phase;
// its completion is enforced by the last B-load's natural vmcnt wait -> no
// explicit vmcnt(0) in the loop, raw s_barrier + lgkmcnt only. B-frags direct
// from L2-resident fragment image (read once per block; wave = 32r x 32c).
// fp32->bf16 pack at ds_read time. Epilogue per panel in buf1, lgkm barriers.

typedef __bf16 bf16x8 __attribute__((ext_vector_type(8)));
typedef float f32x4 __attribute__((ext_vector_type(4)));

#define THREADS 512
#define WBYTES 524288              // 32 chunk-images x 16 KB (fragment order)

__device__ __forceinline__ unsigned bf_rtne(unsigned u) {
  return (u + 0x7fffu + ((u >> 16) & 1u)) >> 16;
}
__device__ __forceinline__ unsigned pack2(float lo, float hi) {
  return bf_rtne(__float_as_uint(lo)) | (bf_rtne(__float_as_uint(hi)) << 16);
}
__device__ __forceinline__ bf16x8 packfrag(const f32x4& a, const f32x4& b) {
  uint4 u;
  u.x = pack2(a[0], a[1]); u.y = pack2(a[2], a[3]);
  u.z = pack2(b[0], b[1]); u.w = pack2(b[2], b[3]);
  return *reinterpret_cast<bf16x8*>(&u);
}
__device__ __forceinline__ void gload_lds16(const void* g, void* l) {
  __builtin_amdgcn_global_load_lds(
      (const __attribute__((address_space(1))) unsigned int*)g,
      (__attribute__((address_space(3))) unsigned int*)l, 16, 0, 0);
}

// W image, fragment order (R13-verified): (c,k): ch=k>>5, q=(k>>3)&3, e=k&7
// byte = ch*16384 + q*4096 + c*16 + e*2 ; wave B-frag = 4 x 256B segments.
__global__ void prep_kernel(const float* __restrict__ Wd, const float* __restrict__ bd,
                            const float* __restrict__ Wo, const float* __restrict__ bo,
                            char* __restrict__ wbuf, float* __restrict__ bias) {
  const int c = blockIdx.x;    // 0..255 output col
  const int t = threadIdx.x;   // 0..255, 4 consecutive k each
  const int i = c >> 4, j = c & 15;
  const float* src;
  float b;
  if (i == j) { src = Wd + i * 1024; b = bd[i]; }
  else { int r = i * 15 + (j < i ? j : j - 1); src = Wo + r * 1024; b = bo[r]; }
  if (t == 0) bias[c] = b;
  const int kk = t * 4;
  const int ch = kk >> 5, q = (kk >> 3) & 3, e = kk & 7;
  float4 v = *reinterpret_cast<const float4*>(src + kk);
  uint2 h;
  h.x = pack2(v.x, v.y);
  h.y = pack2(v.z, v.w);
  *reinterpret_cast<uint2*>(wbuf + ch * 16384 + q * 4096 + c * 16 + e * 2) = h;
}

__global__ __launch_bounds__(THREADS, 2) void cap_main(
    const float* __restrict__ x, const char* __restrict__ wbuf,
    const float* __restrict__ bias, float* __restrict__ out) {
  __shared__ char smem[131072];  // buf0 @0, buf1 @65536 (each: 32 rows x 2KB fp32)

  const int tid = threadIdx.x;
  const int wid = tid >> 6;      // 0..7
  const int lane = tid & 63;
  const int l15 = lane & 15;
  const int l4 = lane >> 4;
  const int wn = wid;            // col group: wave owns cols wn*32..+31 (all 32 rows)

  const size_t blkRow = (size_t)blockIdx.x * 128;

  // B-frag global base: + (h*16+c)*16384 + n*256
  const char* wb = wbuf + l4 * 4096 + (wn * 32 + l15) * 16;

  // stage map: wave stages rows wid*4..wid*4+3 of the panel, 8 insts (rl,q)
  // src byte = row_g*4096 + h*2048 + ((q*1024+lane*16) ^ ((row&7)<<4))  [pre-swz]
  // dst      = buf + row*2048 + q*1024 + lane*16                       [linear]
#define STAGE(PAN, HF)                                                          \
  {                                                                             \
    const char* xb = (const char*)x + (blkRow + (size_t)(PAN) * 32) * 4096 +    \
                     (HF) * 2048;                                               \
    char* db = smem + (HF) * 65536;                                             \
    _Pragma("unroll") for (int i = 0; i < 8; ++i) {                             \
      const int rl = i >> 1, q = i & 1;                                         \
      const int rr_ = wid * 4 + rl;                                             \
      gload_lds16(xb + (size_t)rr_ * 4096 +                                     \
                      (((q * 1024 + lane * 16)) ^ ((rr_ & 7) << 4)),            \
                  db + rr_ * 2048 + q * 1024 + lane * 16);                      \
    }                                                                           \
  }

  // ---- prologue: stage panel0/half0; drain; barrier ----
  STAGE(0, 0);
  asm volatile("s_waitcnt vmcnt(0)" ::: "memory");
  __builtin_amdgcn_s_barrier();

  for (int p = 0; p < 4; ++p) {
    f32x4 acc[2][2];
#pragma unroll
    for (int m = 0; m < 2; ++m)
#pragma unroll
      for (int n = 0; n < 2; ++n) acc[m][n] = (f32x4){0.f, 0.f, 0.f, 0.f};

#pragma unroll
    for (int h = 0; h < 2; ++h) {
      const int hh = p * 2 + h;
      // issue next half's stream FIRST (flies under this half's compute)
      if (hh + 1 < 8) {
        const int pn = (hh + 1) >> 1, hn = (hh + 1) & 1;
        STAGE(pn, hn);
      }

      const char* buf = smem + h * 65536;
#pragma unroll 4
      for (int c = 0; c < 16; ++c) {
        const char* wc = wb + (h * 16 + c) * 16384;
        uint4 bu0 = *reinterpret_cast<const uint4*>(wc);
        uint4 bu1 = *reinterpret_cast<const uint4*>(wc + 256);
        bf16x8 af[2];
#pragma unroll
        for (int m = 0; m < 2; ++m) {
          const char* ap = buf + (m * 16 + l15) * 2048;
          const unsigned ko = (unsigned)(c * 128 + l4 * 32);
          const unsigned sx = (unsigned)((l15 & 7) << 4);
          f32x4 u0 = *reinterpret_cast<const f32x4*>(ap + (ko ^ sx));
          f32x4 u1 = *reinterpret_cast<const f32x4*>(ap + ((ko + 16) ^ sx));
          af[m] = packfrag(u0, u1);
        }
#pragma unroll
        for (int m = 0; m < 2; ++m) {
          acc[m][0] = __builtin_amdgcn_mfma_f32_16x16x32_bf16(
              af[m], *reinterpret_cast<bf16x8*>(&bu0), acc[m][0], 0, 0, 0);
          acc[m][1] = __builtin_amdgcn_mfma_f32_16x16x32_bf16(
              af[m], *reinterpret_cast<bf16x8*>(&bu1), acc[m][1], 0, 0, 0);
        }
      }
      // half boundary: LDS visibility + barrier ONLY (no vmcnt drain; the
      // last B-consume already forced stream(hh+1) completion)
      asm volatile("s_waitcnt lgkmcnt(0)" ::: "memory");
      __builtin_amdgcn_s_barrier();
    }

    // ---- epilogue for panel p (scratch = buf1 area; stream to buf0 flies on) ----
    {
      char* ep = smem + 65536;
      float bsv[2];
      bsv[0] = bias[wn * 32 + l15];
      bsv[1] = bias[wn * 32 + 16 + l15];
#pragma unroll
      for (int m = 0; m < 2; ++m)
#pragma unroll
        for (int n = 0; n < 2; ++n) {
          const int col = wn * 32 + n * 16 + l15;
          const bool diag = (col % 17) == 0;
#pragma unroll
          for (int j2 = 0; j2 < 4; ++j2) {
            const int row = m * 16 + l4 * 4 + j2;
            float v = acc[m][n][j2] + bsv[n];
            float e = __expf(-fabsf(v));
            float sig = (v >= 0.f) ? 1.f / (1.f + e) : e / (1.f + e);
            float sp = fmaxf(v, 0.f) + __logf(1.f + e);
            *reinterpret_cast<float*>(ep + row * 1040 + col * 4) = diag ? sig : -sp;
          }
        }
      asm volatile("s_waitcnt lgkmcnt(0)" ::: "memory");
      __builtin_amdgcn_s_barrier();
      const int rr2 = tid >> 4;          // 0..31
      const int cg = tid & 15;           // 16-float group
      const char* rdp = ep + rr2 * 1040 + cg * 64;
      float4 o0 = *reinterpret_cast<const float4*>(rdp);
      float4 o1 = *reinterpret_cast<const float4*>(rdp + 16);
      float4 o2 = *reinterpret_cast<const float4*>(rdp + 32);
      float4 o3 = *reinterpret_cast<const float4*>(rdp + 48);
      float* orow = out + (blkRow + (size_t)(p * 32 + rr2)) * 256 + cg * 16;
      *reinterpret_cast<float4*>(orow) = o0;
      *reinterpret_cast<float4*>(orow + 4) = o1;
      *reinterpret_cast<float4*>(orow + 8) = o2;
      *reinterpret_cast<float4*>(orow + 12) = o3;
      asm volatile("s_waitcnt lgkmcnt(0)" ::: "memory");
      __builtin_amdgcn_s_barrier();      // protect ep from next panel's stage(buf1)
    }
  }
#undef STAGE
}

extern "C" void kernel_launch(void* const* d_in, const int* in_sizes, int n_in,
                              void* d_out, int out_size, void* d_ws, size_t ws_size,
                              hipStream_t stream) {
  const float* x = (const float*)d_in[0];
  const float* Wd = (const float*)d_in[1];
  const float* bd = (const float*)d_in[2];
  const float* Wo = (const float*)d_in[3];
  const float* bo = (const float*)d_in[4];
  float* out = (float*)d_out;
  char* wbuf = (char*)d_ws;                  // 512 KiB weight image
  float* bias = (float*)(wbuf + WBYTES);     // 1 KiB bias

  prep_kernel<<<dim3(256), dim3(256), 0, stream>>>(Wd, bd, Wo, bo, wbuf, bias);
  cap_main<<<dim3(512), dim3(THREADS), 0, stream>>>(x, wbuf, bias, out);
}